// Round 2
// baseline (620.442 us; speedup 1.0000x reference)
//
#include <hip/hip_runtime.h>

// Problem constants
#define INF  128   // IN_FEATS
#define OUTF 128   // OUT_FEATS
#define NH   8
#define DHD  16    // OUTF/NH
#define QKVW 384   // 3*OUTF

// ---------------- degree histogram ----------------
__global__ void k_deg(const int* __restrict__ src, const int* __restrict__ dst,
                      int* __restrict__ deg_out, int* __restrict__ deg_in, int E) {
    int e = blockIdx.x * blockDim.x + threadIdx.x;
    if (e < E) {
        atomicAdd(&deg_out[src[e]], 1);
        atomicAdd(&deg_in[dst[e]], 1);
    }
}

// ---------------- norm factors ----------------
__global__ void k_norm(const int* __restrict__ deg_out, const int* __restrict__ deg_in,
                       float* __restrict__ norm_src, float* __restrict__ norm_dst, int N) {
    int i = blockIdx.x * blockDim.x + threadIdx.x;
    if (i < N) {
        int a = deg_out[i]; if (a < 1) a = 1;
        int b = deg_in[i];  if (b < 1) b = 1;
        norm_src[i] = 1.0f / sqrtf((float)a);
        norm_dst[i] = 1.0f / sqrtf((float)b);
    }
}

// ---------------- 3-phase exclusive scan of deg_in -> row_start ----------------
__global__ void k_scan1(const int* __restrict__ deg_in, int* __restrict__ row_start,
                        int* __restrict__ bsums, int N) {
    __shared__ int s[256];
    int t = threadIdx.x;
    int i = blockIdx.x * 256 + t;
    int v = (i < N) ? deg_in[i] : 0;
    s[t] = v;
    __syncthreads();
    #pragma unroll
    for (int off = 1; off < 256; off <<= 1) {
        int x = (t >= off) ? s[t - off] : 0;
        __syncthreads();
        s[t] += x;
        __syncthreads();
    }
    if (i < N) row_start[i] = s[t] - v;   // local exclusive
    if (t == 255) bsums[blockIdx.x] = s[255];
}

__global__ void k_scan2(int* __restrict__ bsums, int NB) {
    __shared__ int s[256];
    int t = threadIdx.x;
    int v = (t < NB) ? bsums[t] : 0;
    s[t] = v;
    __syncthreads();
    #pragma unroll
    for (int off = 1; off < 256; off <<= 1) {
        int x = (t >= off) ? s[t - off] : 0;
        __syncthreads();
        s[t] += x;
        __syncthreads();
    }
    if (t < NB) bsums[t] = s[t] - v;      // exclusive block offsets
}

__global__ void k_scan3(int* __restrict__ row_start, const int* __restrict__ bsums,
                        int N, int E) {
    int i = blockIdx.x * 256 + threadIdx.x;
    if (i < N) row_start[i] += bsums[blockIdx.x];
    if (i == N) row_start[N] = E;
}

// ---------------- CSR scatter (edges bucketed by dst) ----------------
__global__ void k_scatter(const int* __restrict__ src, const int* __restrict__ dst,
                          const int* __restrict__ row_start, int* __restrict__ cursor,
                          int* __restrict__ edge_src, int E) {
    int e = blockIdx.x * blockDim.x + threadIdx.x;
    if (e < E) {
        int d = dst[e];
        int p = row_start[d] + atomicAdd(&cursor[d], 1);
        edge_src[p] = src[e];
    }
}

// ---------------- aggregate h[src]*norm_src[src] per dst node (one wave/node) ----------------
__global__ __launch_bounds__(256) void k_agg(const float* __restrict__ h,
                                             const int* __restrict__ row_start,
                                             const int* __restrict__ edge_src,
                                             const float* __restrict__ norm_src,
                                             float* __restrict__ agg, int N) {
    int wid  = (blockIdx.x * 256 + threadIdx.x) >> 6;
    int lane = threadIdx.x & 63;
    if (wid >= N) return;
    int n = wid;
    int c = lane * 2;                      // 2 columns per lane
    int rs = row_start[n], re = row_start[n + 1];
    float a0 = 0.f, a1 = 0.f;
    for (int e = rs; e < re; ++e) {
        int s = edge_src[e];
        float w = norm_src[s];
        float2 f = *reinterpret_cast<const float2*>(h + (size_t)s * INF + c);
        a0 += w * f.x;
        a1 += w * f.y;
    }
    *reinterpret_cast<float2*>(agg + (size_t)n * INF + c) = make_float2(a0, a1);
}

// ---------------- QKV GEMM: qkv[n][j] = relu(dot(agg[n],W[:,j])*norm_dst[n] + b[j]) ----------------
// Block = 384 threads: thread t owns global column t (0-127 Q, 128-255 K, 256-383 V).
// W column cached in 128 VGPRs (f32); agg row streamed as wave-uniform float4 loads.
__global__ __launch_bounds__(384) void k_gemm(const float* __restrict__ agg,
                                              const float* __restrict__ Wq,
                                              const float* __restrict__ Wk,
                                              const float* __restrict__ Wv,
                                              const float* __restrict__ bq,
                                              const float* __restrict__ bk,
                                              const float* __restrict__ bv,
                                              const float* __restrict__ norm_dst,
                                              float* __restrict__ qkv,
                                              int N, int nodes_per_block) {
    int t = threadIdx.x;
    const float* W;
    const float* bb;
    int col;
    if (t < 128)      { W = Wq; bb = bq; col = t; }
    else if (t < 256) { W = Wk; bb = bk; col = t - 128; }
    else              { W = Wv; bb = bv; col = t - 256; }

    float wreg[INF];
    #pragma unroll
    for (int k = 0; k < INF; ++k)
        wreg[k] = W[(size_t)k * OUTF + col];   // coalesced over threads
    float bias = bb[col];

    int n0 = blockIdx.x * nodes_per_block;
    int n1 = n0 + nodes_per_block; if (n1 > N) n1 = N;
    for (int n = n0; n < n1; ++n) {
        const float4* ap = reinterpret_cast<const float4*>(agg + (size_t)n * INF);
        float acc = 0.f;
        #pragma unroll
        for (int k4 = 0; k4 < INF / 4; ++k4) {
            float4 a = ap[k4];
            acc += a.x * wreg[4 * k4 + 0];
            acc += a.y * wreg[4 * k4 + 1];
            acc += a.z * wreg[4 * k4 + 2];
            acc += a.w * wreg[4 * k4 + 3];
        }
        float v = acc * norm_dst[n] + bias;
        qkv[(size_t)n * QKVW + t] = (v > 0.f) ? v : 0.f;
    }
}

// ---------------- attention: per-dst-node softmax-weighted V aggregation (one wave/node) ----------------
__global__ __launch_bounds__(256) void k_attn(const float* __restrict__ qkv,
                                              const int* __restrict__ row_start,
                                              const int* __restrict__ edge_src,
                                              float* __restrict__ out, int N) {
    int wid  = (blockIdx.x * 256 + threadIdx.x) >> 6;
    int lane = threadIdx.x & 63;
    if (wid >= N) return;
    int n = wid;
    int c = lane * 2;                       // cols c, c+1 ; head = c/16 = lane/8
    const float* qrow = qkv + (size_t)n * QKVW;
    float2 q = *reinterpret_cast<const float2*>(qrow + c);
    float acc0 = 0.f, acc1 = 0.f, z = 0.f;
    int rs = row_start[n], re = row_start[n + 1];
    for (int e = rs; e < re; ++e) {
        int s = edge_src[e];
        const float* srow = qkv + (size_t)s * QKVW;
        float2 kv = *reinterpret_cast<const float2*>(srow + OUTF + c);
        float p = q.x * kv.x + q.y * kv.y;
        // reduce over the 8 lanes covering this head's 16 dims
        p += __shfl_xor(p, 1);
        p += __shfl_xor(p, 2);
        p += __shfl_xor(p, 4);
        float sc = 0.25f * p;               // / sqrt(16)
        sc = fminf(fmaxf(sc, -10.f), 10.f);
        float w = __expf(sc);
        float2 vv = *reinterpret_cast<const float2*>(srow + 2 * OUTF + c);
        acc0 += w * vv.x;
        acc1 += w * vv.y;
        z += w;
    }
    float inv = 1.0f / (z + 1e-6f);
    *reinterpret_cast<float2*>(out + (size_t)n * OUTF + c) =
        make_float2(acc0 * inv, acc1 * inv);
}

extern "C" void kernel_launch(void* const* d_in, const int* in_sizes, int n_in,
                              void* d_out, int out_size, void* d_ws, size_t ws_size,
                              hipStream_t stream) {
    const float* h  = (const float*)d_in[0];
    const float* Wq = (const float*)d_in[1];
    const float* bq = (const float*)d_in[2];
    const float* Wk = (const float*)d_in[3];
    const float* bk = (const float*)d_in[4];
    const float* Wv = (const float*)d_in[5];
    const float* bv = (const float*)d_in[6];
    const int* src = (const int*)d_in[7];
    const int* dst = (const int*)d_in[8];

    const int N = in_sizes[0] / INF;   // 50000
    const int E = in_sizes[7];         // 600000

    // workspace carve-up (256B-aligned regions)
    char* ws = (char*)d_ws;
    size_t off = 0;
    auto carve = [&](size_t bytes) -> void* {
        void* p = ws + off;
        off = (off + bytes + 255) & ~(size_t)255;
        return p;
    };
    int*   zeroed    = (int*)  carve((size_t)3 * N * sizeof(int)); // deg_out | deg_in | cursor
    int*   deg_out   = zeroed;
    int*   deg_in    = zeroed + N;
    int*   cursor    = zeroed + 2 * N;
    int*   bsums     = (int*)  carve(1024 * sizeof(int));
    int*   row_start = (int*)  carve((size_t)(N + 1) * sizeof(int));
    int*   edge_src  = (int*)  carve((size_t)E * sizeof(int));
    float* norm_src  = (float*)carve((size_t)N * sizeof(float));
    float* norm_dst  = (float*)carve((size_t)N * sizeof(float));
    float* agg       = (float*)carve((size_t)N * INF * sizeof(float));
    float* qkv       = (float*)carve((size_t)N * QKVW * sizeof(float));
    (void)ws_size;

    float* out = (float*)d_out;

    hipMemsetAsync(zeroed, 0, (size_t)3 * N * sizeof(int), stream);

    int gE = (E + 255) / 256;
    int gN = (N + 255) / 256;
    int NB = (N + 255) / 256;              // scan blocks (196 <= 256)

    k_deg<<<gE, 256, 0, stream>>>(src, dst, deg_out, deg_in, E);
    k_norm<<<gN, 256, 0, stream>>>(deg_out, deg_in, norm_src, norm_dst, N);
    k_scan1<<<NB, 256, 0, stream>>>(deg_in, row_start, bsums, N);
    k_scan2<<<1, 256, 0, stream>>>(bsums, NB);
    k_scan3<<<(N + 1 + 255) / 256, 256, 0, stream>>>(row_start, bsums, N, E);
    k_scatter<<<gE, 256, 0, stream>>>(src, dst, row_start, cursor, edge_src, E);

    int gAgg = (N + 3) / 4;                // 4 waves per 256-block, wave per node
    k_agg<<<gAgg, 256, 0, stream>>>(h, row_start, edge_src, norm_src, agg, N);

    int gemm_blocks = 512;
    int npb = (N + gemm_blocks - 1) / gemm_blocks;
    k_gemm<<<gemm_blocks, 384, 0, stream>>>(agg, Wq, Wk, Wv, bq, bk, bv,
                                            norm_dst, qkv, N, npb);

    k_attn<<<gAgg, 256, 0, stream>>>(qkv, row_start, edge_src, out, N);
}